// Round 3
// baseline (173.181 us; speedup 1.0000x reference)
//
#include <hip/hip_runtime.h>
#include <hip/hip_bf16.h>

#define B_DIM 8192
#define IN_DIM 2048
#define OUT_DIM 2048
#define K2 (2 * IN_DIM)  // hi|lo concatenated K = 4096

typedef __attribute__((ext_vector_type(8))) __bf16 bf16x8;
typedef __attribute__((ext_vector_type(4))) float f32x4;

__device__ __forceinline__ unsigned short f32_to_bf16_rne(float f) {
    unsigned u = __float_as_uint(f);
    unsigned r = (u + 0x7FFFu + ((u >> 16) & 1u)) >> 16;
    return (unsigned short)r;
}
__device__ __forceinline__ float bf16u_to_f32(unsigned short h) {
    return __uint_as_float(((unsigned)h) << 16);
}

__device__ __forceinline__ void gload16(const void* g, void* l) {
    __builtin_amdgcn_global_load_lds(
        (const __attribute__((address_space(1))) void*)g,
        (__attribute__((address_space(3))) void*)l,
        16, 0, 0);
}

// ---------------- Stage 1: per-column partial sums (deterministic) -------------
__global__ void k_stats(const float* __restrict__ x, float* __restrict__ psum,
                        float* __restrict__ psq) {
    int col = blockIdx.x * 256 + threadIdx.x;
    int chunk = blockIdx.y;
    const float* p = x + (size_t)chunk * 256 * IN_DIM + col;
    float s = 0.f, s2 = 0.f;
#pragma unroll 8
    for (int r = 0; r < 256; ++r) {
        float v = p[(size_t)r * IN_DIM];
        s += v;
        s2 = fmaf(v, v, s2);
    }
    psum[chunk * IN_DIM + col] = s;
    psq[chunk * IN_DIM + col] = s2;
}

// ---------------- Stage 2: finalize mean/var -> scale/shift --------------------
__global__ void k_finalize(const float* __restrict__ psum, const float* __restrict__ psq,
                           const float* __restrict__ gamma, const float* __restrict__ beta,
                           float* __restrict__ scale, float* __restrict__ shift) {
    int c = blockIdx.x * 256 + threadIdx.x;
    float s = 0.f, s2 = 0.f;
#pragma unroll
    for (int ch = 0; ch < 32; ++ch) {
        s += psum[ch * IN_DIM + c];
        s2 += psq[ch * IN_DIM + c];
    }
    float mean = s * (1.0f / B_DIM);
    float var = fmaf(-mean, mean, s2 * (1.0f / B_DIM));
    float sc = gamma[c] * rsqrtf(var + 1e-5f);
    scale[c] = sc;
    shift[c] = fmaf(-mean, sc, beta[c]);
}

// ---------------- Stage 3: xn -> bf16 hi|lo concatenated A [8192][4096] --------
__global__ void k_prep_a(const float* __restrict__ x, const float* __restrict__ scale,
                         const float* __restrict__ shift, unsigned short* __restrict__ Acat) {
    int row = blockIdx.x;
    int c0 = threadIdx.x * 8;
    const float4* px = (const float4*)(x + (size_t)row * IN_DIM + c0);
    float4 v0 = px[0], v1 = px[1];
    const float4* ps = (const float4*)(scale + c0);
    float4 s0 = ps[0], s1 = ps[1];
    const float4* pb = (const float4*)(shift + c0);
    float4 b0 = pb[0], b1 = pb[1];
    float xs[8] = {v0.x, v0.y, v0.z, v0.w, v1.x, v1.y, v1.z, v1.w};
    float ss[8] = {s0.x, s0.y, s0.z, s0.w, s1.x, s1.y, s1.z, s1.w};
    float bb[8] = {b0.x, b0.y, b0.z, b0.w, b1.x, b1.y, b1.z, b1.w};
    union { unsigned short u[8]; uint4 v; } hi, lo;
#pragma unroll
    for (int j = 0; j < 8; ++j) {
        float xn = fmaf(xs[j], ss[j], bb[j]);
        unsigned short h = f32_to_bf16_rne(xn);
        float r = xn - bf16u_to_f32(h);
        hi.u[j] = h;
        lo.u[j] = f32_to_bf16_rne(r);
    }
    size_t base = (size_t)row * K2;
    *(uint4*)(Acat + base + c0) = hi.v;
    *(uint4*)(Acat + base + IN_DIM + c0) = lo.v;
}

// ---------------- Stage 4: weight sign -> bf16 +-1 [2048][2048] ----------------
__global__ void k_prep_b(const float* __restrict__ w, unsigned short* __restrict__ Bsgn) {
    int row = blockIdx.x;
    int c0 = threadIdx.x * 8;
    const float4* pw = (const float4*)(w + (size_t)row * IN_DIM + c0);
    float4 v0 = pw[0], v1 = pw[1];
    float wv[8] = {v0.x, v0.y, v0.z, v0.w, v1.x, v1.y, v1.z, v1.w};
    union { unsigned short u[8]; uint4 v; } sb;
#pragma unroll
    for (int j = 0; j < 8; ++j) sb.u[j] = (wv[j] >= 0.0f) ? 0x3F80u : 0xBF80u;
    *(uint4*)(Bsgn + (size_t)row * IN_DIM + c0) = sb.v;
}

// ---------------- Stage 5: 256x256-tile 8-wave 4-phase MFMA GEMM ---------------
// Deep-pipeline variant: ALL next-tile loads issued at tile top / p1
// (issue-early), counted waits drain only what the next phase needs
// (wait-late). Steady-state in-flight depth: 8 -> never below 2.
#define BM 256
#define BN 256
#define BK 64
#define MT (B_DIM / BM)    // 32
#define NT (OUT_DIM / BN)  // 8
#define NWG (MT * NT)      // 256
#define NKT (K2 / BK)      // 64
#define TILE_E (BM * BK)   // 16384 elems = 32 KB

#define MEMF() asm volatile("" ::: "memory")
#define BARRIER() do { MEMF(); __builtin_amdgcn_s_barrier(); MEMF(); } while (0)
#define WAITVM(N) asm volatile("s_waitcnt vmcnt(" #N ")" ::: "memory")

__global__ __launch_bounds__(512, 2) void k_gemm(const unsigned short* __restrict__ A,
                                                 const unsigned short* __restrict__ Bsgn,
                                                 float* __restrict__ out) {
    __shared__ __align__(16) unsigned short sh[4 * TILE_E];  // [buf][A,B] = 128 KiB

    // T1: XCD-aware swizzle (256 % 8 == 0 -> bijective)
    int bid = blockIdx.x;
    int swz = (bid & 7) * (NWG / 8) + (bid >> 3);
    int mt = swz >> 3, nt = swz & 7;
    int m0 = mt * BM, n0 = nt * BN;

    int t = threadIdx.x;
    int lane = t & 63, w = t >> 6;
    int wm = w >> 2, wn = w & 3;       // 2 x 4 wave grid; per-wave out = 128 x 64
    int lrow = lane & 15, lg = lane >> 4, lx = lane & 7;

    // T2 read-side swizzle: slot(16B) ^= row&7; row&7 == lane&7 for all frags
    int s0 = ((lg ^ lx) << 3);         // ks=0: logical slot lg
    int s1 = (((lg + 4) ^ lx) << 3);   // ks=1: logical slot lg+4
    int aRdBase = (wm * 128 + lrow) * BK;
    int bRdBase = (wn * 64 + lrow) * BK;

    // staging: thread t covers row trow of each 64-row chunk; source slot is
    // pre-swizzled so linear LDS dest + swizzled read = identity (rule 21)
    int trow = t >> 3;
    int tslot = (t & 7) ^ (trow & 7);

    auto stageA = [&](unsigned short* dst, int crow, int kt) {
        const unsigned short* src =
            A + (size_t)(m0 + crow + trow) * K2 + kt * BK + (tslot << 3);
        gload16(src, dst + crow * BK + t * 8);
    };
    auto stageB = [&](unsigned short* dst, int crow, int kt) {
        const unsigned short* src =
            Bsgn + (size_t)(n0 + crow + trow) * IN_DIM + ((kt * BK) & (IN_DIM - 1)) + (tslot << 3);
        gload16(src, dst + crow * BK + t * 8);
    };

    f32x4 acc[8][4] = {};

    // Prologue: stage tile 0 in FIFO order matching first consumption;
    // leave the last 2 (A64, A192 — not needed until p2) in flight.
    {
        unsigned short* A0 = sh;
        unsigned short* B0 = sh + TILE_E;
        stageB(B0, 0, 0);
        stageB(B0, 64, 0);
        stageB(B0, 128, 0);
        stageB(B0, 192, 0);
        stageA(A0, 0, 0);
        stageA(A0, 128, 0);
        stageA(A0, 64, 0);
        stageA(A0, 192, 0);
        WAITVM(2);
        BARRIER();
    }

    for (int T = 0; T < NKT; ++T) {
        int cur = T & 1, nxt = cur ^ 1;
        const unsigned short* Ab = sh + (cur * 2 + 0) * TILE_E;
        const unsigned short* Bb = sh + (cur * 2 + 1) * TILE_E;
        unsigned short* An = sh + (nxt * 2 + 0) * TILE_E;
        unsigned short* Bn = sh + (nxt * 2 + 1) * TILE_E;
        bool pf = (T < NKT - 1);

        // Issue-early: 6 next-tile loads at tile top (B first — consumed first
        // next tile), before any LDS reads. Buffer `nxt` is free all tile.
        if (pf) {
            stageB(Bn, 0, T + 1);
            stageB(Bn, 64, T + 1);
            stageB(Bn, 128, T + 1);
            stageB(Bn, 192, T + 1);
            stageA(An, 0, T + 1);
            stageA(An, 128, T + 1);
        }

        // B fragments for the whole tile (persist in regs across phases)
        bf16x8 bf[4][2];
#pragma unroll
        for (int n = 0; n < 4; ++n) {
            bf[n][0] = *(const bf16x8*)&Bb[bRdBase + n * (16 * BK) + s0];
            bf[n][1] = *(const bf16x8*)&Bb[bRdBase + n * (16 * BK) + s1];
        }

#pragma unroll
        for (int p = 0; p < 4; ++p) {
            // A fragments for this phase's m-quadrant
            bf16x8 af[2][2];
#pragma unroll
            for (int mi = 0; mi < 2; ++mi) {
                af[mi][0] = *(const bf16x8*)&Ab[aRdBase + (2 * p + mi) * (16 * BK) + s0];
                af[mi][1] = *(const bf16x8*)&Ab[aRdBase + (2 * p + mi) * (16 * BK) + s1];
            }
            if (pf && p == 1) {  // last 2 loads: A64/A192, consumed next tile p2
                stageA(An, 64, T + 1);
                stageA(An, 192, T + 1);
            }
            BARRIER();
            __builtin_amdgcn_s_setprio(1);
#pragma unroll
            for (int mi = 0; mi < 2; ++mi)
#pragma unroll
                for (int n = 0; n < 4; ++n)
#pragma unroll
                    for (int ks = 0; ks < 2; ++ks)
                        acc[2 * p + mi][n] = __builtin_amdgcn_mfma_f32_16x16x32_bf16(
                            af[mi][ks], bf[n][ks], acc[2 * p + mi][n], 0, 0, 0);
            __builtin_amdgcn_s_setprio(0);
            // Counted waits (T4): p1-end drains ONLY the prev tile's A64/A192
            // leftovers (needed by p2's ds_read); p3-end drains the 6 chunks
            // the next tile consumes first. Steady-state floor: 2 in flight.
            if (p == 1) {
                if (pf) { WAITVM(8); } else { WAITVM(0); }
            }
            if (p == 3 && pf) { WAITVM(2); }
            BARRIER();
        }
    }

    // Epilogue: C/D map col=lane&15, row=(lane>>4)*4+reg; fused hardtanh
#pragma unroll
    for (int m = 0; m < 8; ++m) {
#pragma unroll
        for (int n = 0; n < 4; ++n) {
#pragma unroll
            for (int r = 0; r < 4; ++r) {
                int row = m0 + wm * 128 + m * 16 + lg * 4 + r;
                int col = n0 + wn * 64 + n * 16 + lrow;
                float v = acc[m][n][r];
                v = fminf(fmaxf(v, -1.0f), 1.0f);
                out[(size_t)row * OUT_DIM + col] = v;
            }
        }
    }
}

extern "C" void kernel_launch(void* const* d_in, const int* in_sizes, int n_in,
                              void* d_out, int out_size, void* d_ws, size_t ws_size,
                              hipStream_t stream) {
    const float* x = (const float*)d_in[0];
    const float* w = (const float*)d_in[1];
    const float* gamma = (const float*)d_in[2];
    const float* beta = (const float*)d_in[3];
    float* out = (float*)d_out;

    float* wsf = (float*)d_ws;
    float* psum = wsf;                                   // 32*2048 f32
    float* psq = wsf + 32 * IN_DIM;                      // 32*2048 f32
    float* scale = wsf + 64 * IN_DIM;                    // 2048 f32
    float* shift = wsf + 65 * IN_DIM;                    // 2048 f32
    unsigned short* Bsgn = (unsigned short*)(wsf + 66 * IN_DIM);  // 8 MB
    unsigned short* Acat = Bsgn + (size_t)OUT_DIM * IN_DIM;       // 64 MB

    k_stats<<<dim3(8, 32), 256, 0, stream>>>(x, psum, psq);
    k_finalize<<<8, 256, 0, stream>>>(psum, psq, gamma, beta, scale, shift);
    k_prep_a<<<B_DIM, 256, 0, stream>>>(x, scale, shift, Acat);
    k_prep_b<<<OUT_DIM, 256, 0, stream>>>(w, Bsgn);
    k_gemm<<<NWG, 512, 0, stream>>>(Acat, Bsgn, out);
}

// Round 4
// 168.105 us; speedup vs baseline: 1.0302x; 1.0302x over previous
//
#include <hip/hip_runtime.h>
#include <hip/hip_bf16.h>

#define B_DIM 8192
#define IN_DIM 2048
#define OUT_DIM 2048
#define K2 (2 * IN_DIM)  // hi|lo concatenated K = 4096

typedef __attribute__((ext_vector_type(8))) __bf16 bf16x8;
typedef __attribute__((ext_vector_type(4))) float f32x4;

__device__ __forceinline__ unsigned short f32_to_bf16_rne(float f) {
    unsigned u = __float_as_uint(f);
    unsigned r = (u + 0x7FFFu + ((u >> 16) & 1u)) >> 16;
    return (unsigned short)r;
}
__device__ __forceinline__ float bf16u_to_f32(unsigned short h) {
    return __uint_as_float(((unsigned)h) << 16);
}

__device__ __forceinline__ void gload16(const void* g, void* l) {
    __builtin_amdgcn_global_load_lds(
        (const __attribute__((address_space(1))) void*)g,
        (__attribute__((address_space(3))) void*)l,
        16, 0, 0);
}

// ---------------- Stage 1: per-column partial sums (deterministic) -------------
__global__ void k_stats(const float* __restrict__ x, float* __restrict__ psum,
                        float* __restrict__ psq) {
    int col = blockIdx.x * 256 + threadIdx.x;
    int chunk = blockIdx.y;
    const float* p = x + (size_t)chunk * 256 * IN_DIM + col;
    float s = 0.f, s2 = 0.f;
#pragma unroll 8
    for (int r = 0; r < 256; ++r) {
        float v = p[(size_t)r * IN_DIM];
        s += v;
        s2 = fmaf(v, v, s2);
    }
    psum[chunk * IN_DIM + col] = s;
    psq[chunk * IN_DIM + col] = s2;
}

// ---------------- Stage 2: finalize mean/var -> scale/shift --------------------
__global__ void k_finalize(const float* __restrict__ psum, const float* __restrict__ psq,
                           const float* __restrict__ gamma, const float* __restrict__ beta,
                           float* __restrict__ scale, float* __restrict__ shift) {
    int c = blockIdx.x * 256 + threadIdx.x;
    float s = 0.f, s2 = 0.f;
#pragma unroll
    for (int ch = 0; ch < 32; ++ch) {
        s += psum[ch * IN_DIM + c];
        s2 += psq[ch * IN_DIM + c];
    }
    float mean = s * (1.0f / B_DIM);
    float var = fmaf(-mean, mean, s2 * (1.0f / B_DIM));
    float sc = gamma[c] * rsqrtf(var + 1e-5f);
    scale[c] = sc;
    shift[c] = fmaf(-mean, sc, beta[c]);
}

// ---------------- Stage 3: xn -> bf16 hi|lo concatenated A [8192][4096] --------
__global__ void k_prep_a(const float* __restrict__ x, const float* __restrict__ scale,
                         const float* __restrict__ shift, unsigned short* __restrict__ Acat) {
    int row = blockIdx.x;
    int c0 = threadIdx.x * 8;
    const float4* px = (const float4*)(x + (size_t)row * IN_DIM + c0);
    float4 v0 = px[0], v1 = px[1];
    const float4* ps = (const float4*)(scale + c0);
    float4 s0 = ps[0], s1 = ps[1];
    const float4* pb = (const float4*)(shift + c0);
    float4 b0 = pb[0], b1 = pb[1];
    float xs[8] = {v0.x, v0.y, v0.z, v0.w, v1.x, v1.y, v1.z, v1.w};
    float ss[8] = {s0.x, s0.y, s0.z, s0.w, s1.x, s1.y, s1.z, s1.w};
    float bb[8] = {b0.x, b0.y, b0.z, b0.w, b1.x, b1.y, b1.z, b1.w};
    union { unsigned short u[8]; uint4 v; } hi, lo;
#pragma unroll
    for (int j = 0; j < 8; ++j) {
        float xn = fmaf(xs[j], ss[j], bb[j]);
        unsigned short h = f32_to_bf16_rne(xn);
        float r = xn - bf16u_to_f32(h);
        hi.u[j] = h;
        lo.u[j] = f32_to_bf16_rne(r);
    }
    size_t base = (size_t)row * K2;
    *(uint4*)(Acat + base + c0) = hi.v;
    *(uint4*)(Acat + base + IN_DIM + c0) = lo.v;
}

// ---------------- Stage 4: weight sign -> bf16 +-1 [2048][2048] ----------------
__global__ void k_prep_b(const float* __restrict__ w, unsigned short* __restrict__ Bsgn) {
    int row = blockIdx.x;
    int c0 = threadIdx.x * 8;
    const float4* pw = (const float4*)(w + (size_t)row * IN_DIM + c0);
    float4 v0 = pw[0], v1 = pw[1];
    float wv[8] = {v0.x, v0.y, v0.z, v0.w, v1.x, v1.y, v1.z, v1.w};
    union { unsigned short u[8]; uint4 v; } sb;
#pragma unroll
    for (int j = 0; j < 8; ++j) sb.u[j] = (wv[j] >= 0.0f) ? 0x3F80u : 0xBF80u;
    *(uint4*)(Bsgn + (size_t)row * IN_DIM + c0) = sb.v;
}

// ---------------- Stage 5: 256x256-tile, 8-wave (4m x 2n), 4-phase GEMM --------
// Consumption order == stage order, wave-uniform: each wave's needed chunks sit
// at fixed positions in its own vmcnt FIFO, so counted waits are exact and every
// load gets >=2 phases of latency slack. MFMA ks-outer (deps 8 apart).
#define BM 256
#define BN 256
#define BK 64
#define MT (B_DIM / BM)    // 32
#define NT (OUT_DIM / BN)  // 8
#define NWG (MT * NT)      // 256
#define NKT (K2 / BK)      // 64
#define TILE_E (BM * BK)   // 16384 elems = 32 KB

#define MEMF() asm volatile("" ::: "memory")
#define BARRIER() do { MEMF(); __builtin_amdgcn_s_barrier(); MEMF(); } while (0)
#define WAITVM(N) asm volatile("s_waitcnt vmcnt(" #N ")" ::: "memory")

__global__ __launch_bounds__(512, 2) void k_gemm(const unsigned short* __restrict__ A,
                                                 const unsigned short* __restrict__ Bsgn,
                                                 float* __restrict__ out) {
    __shared__ __align__(16) unsigned short sh[4 * TILE_E];  // 128 KiB

    // T1: XCD-aware swizzle (256 % 8 == 0 -> bijective)
    int bid = blockIdx.x;
    int swz = (bid & 7) * (NWG / 8) + (bid >> 3);
    int mt = swz >> 3, nt = swz & 7;
    int m0 = mt * BM, n0 = nt * BN;

    int t = threadIdx.x;
    int lane = t & 63, w = t >> 6;
    int wm = w >> 1, wn = w & 1;         // 4m x 2n waves; per-wave out 64 x 128
    int lrow = lane & 15, lg = lane >> 4;
    int lq = lane >> 3, lslot = lane & 7;
    int tsl = lslot ^ lq;                // pre-swizzled source slot (row&7 == lq)

    int sl0 = (lg ^ (lane & 7)) << 3;          // ks=0 read slot offset (elems)
    int sl1 = ((lg + 4) ^ (lane & 7)) << 3;    // ks=1

    int aRd = (wm * 64 + lrow) * BK;
    int bRd = (wn * 128 + lrow) * BK;

    // A-chunk(wm): pieces q = wn*4 + j (j=0..3), each 1 KB (8 rows x 64 elems)
    auto stageA = [&](unsigned short* abuf, int j, int kt) {
        int q = wn * 4 + j;
        const unsigned short* src =
            A + (size_t)(m0 + wm * 64 + q * 8 + lq) * K2 + kt * BK + tsl * 8;
        gload16(src, abuf + wm * (64 * BK) + q * 512 + lane * 8);
    };
    // B-chunk(2wn+i): pieces q = wm*2 + j (j=0..1)
    auto stageB = [&](unsigned short* bbuf, int i, int j, int kt) {
        int cb = 2 * wn + i;
        int q = wm * 2 + j;
        const unsigned short* src =
            Bsgn + (size_t)(n0 + cb * 64 + q * 8 + lq) * IN_DIM +
            ((kt * BK) & (IN_DIM - 1)) + tsl * 8;
        gload16(src, bbuf + cb * (64 * BK) + q * 512 + lane * 8);
    };

    f32x4 acc[4][8] = {};

#define LDA(buf, m, sl) (*(const bf16x8*)&(buf)[aRd + (m) * (16 * BK) + (sl)])
#define LDB(buf, n, sl) (*(const bf16x8*)&(buf)[bRd + (n) * (16 * BK) + (sl)])
#define MFMA_PAIR(NP)                                                              \
    do {                                                                           \
        __builtin_amdgcn_s_setprio(1);                                             \
        _Pragma("unroll") for (int ks = 0; ks < 2; ++ks)                           \
            _Pragma("unroll") for (int m = 0; m < 4; ++m)                          \
                _Pragma("unroll") for (int i = 0; i < 2; ++i)                      \
                    acc[m][(NP) + i] = __builtin_amdgcn_mfma_f32_16x16x32_bf16(    \
                        af[m][ks], bp[i][ks], acc[m][(NP) + i], 0, 0, 0);          \
        __builtin_amdgcn_s_setprio(0);                                             \
    } while (0)

    // Prologue: per-wave stage order A x4, B(2wn) x2, B(2wn+1) x2; keep last 2
    // in flight (B(2wn+1) not read until ph2).
    {
        unsigned short* A0 = (unsigned short*)sh;
        unsigned short* B0 = A0 + TILE_E;
        stageA(A0, 0, 0); stageA(A0, 1, 0); stageA(A0, 2, 0); stageA(A0, 3, 0);
        stageB(B0, 0, 0, 0); stageB(B0, 0, 1, 0);
        stageB(B0, 1, 0, 0); stageB(B0, 1, 1, 0);
        WAITVM(2);
        BARRIER();
    }

#pragma unroll 2
    for (int T = 0; T < NKT; ++T) {
        const unsigned short* Ab = sh + (T & 1) * (2 * TILE_E);
        const unsigned short* Bb = Ab + TILE_E;
        unsigned short* An = (unsigned short*)sh + ((T & 1) ^ 1) * (2 * TILE_E);
        unsigned short* Bn = An + TILE_E;
        bool pf = (T < NKT - 1);
        int kn = T + 1;

        // ---- phase 0: n-frags {0,1} (B-chunk 2wn) ----
        bf16x8 af[4][2];
#pragma unroll
        for (int m = 0; m < 4; ++m) {
            af[m][0] = LDA(Ab, m, sl0);
            af[m][1] = LDA(Ab, m, sl1);
        }
        {
            bf16x8 bp[2][2];
#pragma unroll
            for (int i = 0; i < 2; ++i) { bp[i][0] = LDB(Bb, i, sl0); bp[i][1] = LDB(Bb, i, sl1); }
            if (pf) { stageA(An, 0, kn); stageA(An, 1, kn); }
            BARRIER();
            MFMA_PAIR(0);
            BARRIER();
        }
        // ---- phase 1: n-frags {2,3} ----
        {
            bf16x8 bp[2][2];
#pragma unroll
            for (int i = 0; i < 2; ++i) { bp[i][0] = LDB(Bb, 2 + i, sl0); bp[i][1] = LDB(Bb, 2 + i, sl1); }
            if (pf) { stageA(An, 2, kn); stageA(An, 3, kn); }
            BARRIER();
            MFMA_PAIR(2);
            if (pf) { WAITVM(4); } else { WAITVM(0); }  // drain B(2wn+1) for ph2
            BARRIER();
        }
        // ---- phase 2: n-frags {4,5} (B-chunk 2wn+1) ----
        {
            bf16x8 bp[2][2];
#pragma unroll
            for (int i = 0; i < 2; ++i) { bp[i][0] = LDB(Bb, 4 + i, sl0); bp[i][1] = LDB(Bb, 4 + i, sl1); }
            if (pf) { stageB(Bn, 0, 0, kn); stageB(Bn, 0, 1, kn); }
            BARRIER();
            MFMA_PAIR(4);
            BARRIER();
        }
        // ---- phase 3: n-frags {6,7} ----
        {
            bf16x8 bp[2][2];
#pragma unroll
            for (int i = 0; i < 2; ++i) { bp[i][0] = LDB(Bb, 6 + i, sl0); bp[i][1] = LDB(Bb, 6 + i, sl1); }
            if (pf) { stageB(Bn, 1, 0, kn); stageB(Bn, 1, 1, kn); }
            BARRIER();
            MFMA_PAIR(6);
            if (pf) { WAITVM(2); }  // drain next tile's A + B(2wn); keep 2 in flight
            BARRIER();
        }
    }

    // Epilogue: C/D map col=lane&15, row=(lane>>4)*4+reg; fused hardtanh
#pragma unroll
    for (int m = 0; m < 4; ++m) {
#pragma unroll
        for (int n = 0; n < 8; ++n) {
#pragma unroll
            for (int r = 0; r < 4; ++r) {
                int row = m0 + wm * 64 + m * 16 + lg * 4 + r;
                int col = n0 + wn * 128 + n * 16 + lrow;
                float v = acc[m][n][r];
                v = fminf(fmaxf(v, -1.0f), 1.0f);
                out[(size_t)row * OUT_DIM + col] = v;
            }
        }
    }
}

extern "C" void kernel_launch(void* const* d_in, const int* in_sizes, int n_in,
                              void* d_out, int out_size, void* d_ws, size_t ws_size,
                              hipStream_t stream) {
    const float* x = (const float*)d_in[0];
    const float* w = (const float*)d_in[1];
    const float* gamma = (const float*)d_in[2];
    const float* beta = (const float*)d_in[3];
    float* out = (float*)d_out;

    float* wsf = (float*)d_ws;
    float* psum = wsf;                                   // 32*2048 f32
    float* psq = wsf + 32 * IN_DIM;                      // 32*2048 f32
    float* scale = wsf + 64 * IN_DIM;                    // 2048 f32
    float* shift = wsf + 65 * IN_DIM;                    // 2048 f32
    unsigned short* Bsgn = (unsigned short*)(wsf + 66 * IN_DIM);  // 8 MB
    unsigned short* Acat = Bsgn + (size_t)OUT_DIM * IN_DIM;       // 64 MB

    k_stats<<<dim3(8, 32), 256, 0, stream>>>(x, psum, psq);
    k_finalize<<<8, 256, 0, stream>>>(psum, psq, gamma, beta, scale, shift);
    k_prep_a<<<B_DIM, 256, 0, stream>>>(x, scale, shift, Acat);
    k_prep_b<<<OUT_DIM, 256, 0, stream>>>(w, Bsgn);
    k_gemm<<<NWG, 512, 0, stream>>>(Acat, Bsgn, out);
}

// Round 5
// 160.988 us; speedup vs baseline: 1.0757x; 1.0442x over previous
//
#include <hip/hip_runtime.h>
#include <hip/hip_bf16.h>

#define B_DIM 8192
#define IN_DIM 2048
#define OUT_DIM 2048
#define K2 (2 * IN_DIM)  // hi|lo concatenated K = 4096

typedef __attribute__((ext_vector_type(8))) __bf16 bf16x8;
typedef __attribute__((ext_vector_type(4))) float f32x4;

__device__ __forceinline__ unsigned short f32_to_bf16_rne(float f) {
    unsigned u = __float_as_uint(f);
    unsigned r = (u + 0x7FFFu + ((u >> 16) & 1u)) >> 16;
    return (unsigned short)r;
}
__device__ __forceinline__ float bf16u_to_f32(unsigned short h) {
    return __uint_as_float(((unsigned)h) << 16);
}

__device__ __forceinline__ void gload16(const void* g, void* l) {
    __builtin_amdgcn_global_load_lds(
        (const __attribute__((address_space(1))) void*)g,
        (__attribute__((address_space(3))) void*)l,
        16, 0, 0);
}

// ---------------- Stage 1: per-column partial sums (deterministic) -------------
__global__ void k_stats(const float* __restrict__ x, float* __restrict__ psum,
                        float* __restrict__ psq) {
    int col = blockIdx.x * 256 + threadIdx.x;
    int chunk = blockIdx.y;
    const float* p = x + (size_t)chunk * 256 * IN_DIM + col;
    float s = 0.f, s2 = 0.f;
#pragma unroll 8
    for (int r = 0; r < 256; ++r) {
        float v = p[(size_t)r * IN_DIM];
        s += v;
        s2 = fmaf(v, v, s2);
    }
    psum[chunk * IN_DIM + col] = s;
    psq[chunk * IN_DIM + col] = s2;
}

// ---------------- Stage 2: finalize mean/var -> scale/shift --------------------
__global__ void k_finalize(const float* __restrict__ psum, const float* __restrict__ psq,
                           const float* __restrict__ gamma, const float* __restrict__ beta,
                           float* __restrict__ scale, float* __restrict__ shift) {
    int c = blockIdx.x * 256 + threadIdx.x;
    float s = 0.f, s2 = 0.f;
#pragma unroll
    for (int ch = 0; ch < 32; ++ch) {
        s += psum[ch * IN_DIM + c];
        s2 += psq[ch * IN_DIM + c];
    }
    float mean = s * (1.0f / B_DIM);
    float var = fmaf(-mean, mean, s2 * (1.0f / B_DIM));
    float sc = gamma[c] * rsqrtf(var + 1e-5f);
    scale[c] = sc;
    shift[c] = fmaf(-mean, sc, beta[c]);
}

// ---------------- Stage 3: xn -> bf16 hi|lo concatenated A [8192][4096] --------
__global__ void k_prep_a(const float* __restrict__ x, const float* __restrict__ scale,
                         const float* __restrict__ shift, unsigned short* __restrict__ Acat) {
    int row = blockIdx.x;
    int c0 = threadIdx.x * 8;
    const float4* px = (const float4*)(x + (size_t)row * IN_DIM + c0);
    float4 v0 = px[0], v1 = px[1];
    const float4* ps = (const float4*)(scale + c0);
    float4 s0 = ps[0], s1 = ps[1];
    const float4* pb = (const float4*)(shift + c0);
    float4 b0 = pb[0], b1 = pb[1];
    float xs[8] = {v0.x, v0.y, v0.z, v0.w, v1.x, v1.y, v1.z, v1.w};
    float ss[8] = {s0.x, s0.y, s0.z, s0.w, s1.x, s1.y, s1.z, s1.w};
    float bb[8] = {b0.x, b0.y, b0.z, b0.w, b1.x, b1.y, b1.z, b1.w};
    union { unsigned short u[8]; uint4 v; } hi, lo;
#pragma unroll
    for (int j = 0; j < 8; ++j) {
        float xn = fmaf(xs[j], ss[j], bb[j]);
        unsigned short h = f32_to_bf16_rne(xn);
        float r = xn - bf16u_to_f32(h);
        hi.u[j] = h;
        lo.u[j] = f32_to_bf16_rne(r);
    }
    size_t base = (size_t)row * K2;
    *(uint4*)(Acat + base + c0) = hi.v;
    *(uint4*)(Acat + base + IN_DIM + c0) = lo.v;
}

// ---------------- Stage 4: weight sign -> bf16 +-1 [2048][2048] ----------------
__global__ void k_prep_b(const float* __restrict__ w, unsigned short* __restrict__ Bsgn) {
    int row = blockIdx.x;
    int c0 = threadIdx.x * 8;
    const float4* pw = (const float4*)(w + (size_t)row * IN_DIM + c0);
    float4 v0 = pw[0], v1 = pw[1];
    float wv[8] = {v0.x, v0.y, v0.z, v0.w, v1.x, v1.y, v1.z, v1.w};
    union { unsigned short u[8]; uint4 v; } sb;
#pragma unroll
    for (int j = 0; j < 8; ++j) sb.u[j] = (wv[j] >= 0.0f) ? 0x3F80u : 0xBF80u;
    *(uint4*)(Bsgn + (size_t)row * IN_DIM + c0) = sb.v;
}

// ---------------- Stage 5: 256x256 tile, 8-wave, reg-prefetched pipeline -------
// Fragments for phase p+1 are ds_read during phase p (register double-buffer),
// so LDS latency hides under MFMA. Only 2 barriers per K-tile (the cross-wave
// staging hazards): ph1-top (B-chunk1 landed) and ph3-top (next tile staged).
#define BM 256
#define BN 256
#define BK 64
#define MT (B_DIM / BM)    // 32
#define NT (OUT_DIM / BN)  // 8
#define NWG (MT * NT)      // 256
#define NKT (K2 / BK)      // 64
#define TILE_E (BM * BK)   // 16384 elems = 32 KB

#define MEMF() asm volatile("" ::: "memory")
#define BARRIER() do { MEMF(); __builtin_amdgcn_s_barrier(); MEMF(); } while (0)
#define WAITVM(N) asm volatile("s_waitcnt vmcnt(" #N ")" ::: "memory")
#define WAITLGKM0() asm volatile("s_waitcnt lgkmcnt(0)" ::: "memory")

__global__ __launch_bounds__(512, 2) void k_gemm(const unsigned short* __restrict__ A,
                                                 const unsigned short* __restrict__ Bsgn,
                                                 float* __restrict__ out) {
    __shared__ __align__(16) unsigned short sh[4 * TILE_E];  // 128 KiB

    // T1: XCD-aware swizzle (256 % 8 == 0 -> bijective)
    int bid = blockIdx.x;
    int swz = (bid & 7) * (NWG / 8) + (bid >> 3);
    int mt = swz >> 3, nt = swz & 7;
    int m0 = mt * BM, n0 = nt * BN;

    int t = threadIdx.x;
    int lane = t & 63, w = t >> 6;
    int wm = w >> 1, wn = w & 1;         // 4m x 2n waves; per-wave out 64 x 128
    int lrow = lane & 15, lg = lane >> 4;
    int lq = lane >> 3, lslot = lane & 7;
    int tsl = lslot ^ lq;                // pre-swizzled source slot (row&7 == lq)

    int sl0 = (lg ^ (lane & 7)) << 3;          // ks=0 read slot offset (elems)
    int sl1 = ((lg + 4) ^ (lane & 7)) << 3;    // ks=1

    int aRd = (wm * 64 + lrow) * BK;
    int bRd = (wn * 128 + lrow) * BK;

    // A-chunk(wm): pieces q = wn*4 + j (j=0..3), each 8 rows x 128B
    auto stageA = [&](unsigned short* abuf, int j, int kt) {
        int q = wn * 4 + j;
        const unsigned short* src =
            A + (size_t)(m0 + wm * 64 + q * 8 + lq) * K2 + kt * BK + tsl * 8;
        gload16(src, abuf + wm * (64 * BK) + q * 512 + lane * 8);
    };
    // B-chunk(2wn+i): pieces q = wm*2 + j (j=0..1)
    auto stageB = [&](unsigned short* bbuf, int i, int j, int kt) {
        int cb = 2 * wn + i;
        int q = wm * 2 + j;
        const unsigned short* src =
            Bsgn + (size_t)(n0 + cb * 64 + q * 8 + lq) * IN_DIM +
            ((kt * BK) & (IN_DIM - 1)) + tsl * 8;
        gload16(src, bbuf + cb * (64 * BK) + q * 512 + lane * 8);
    };

    f32x4 acc[4][8] = {};

#define LDA(buf, m, sl) (*(const bf16x8*)&(buf)[aRd + (m) * (16 * BK) + (sl)])
#define LDB(buf, n, sl) (*(const bf16x8*)&(buf)[bRd + (n) * (16 * BK) + (sl)])
#define MFMA_PAIR(NP, BP)                                                          \
    do {                                                                           \
        __builtin_amdgcn_s_setprio(1);                                             \
        _Pragma("unroll") for (int ks = 0; ks < 2; ++ks)                           \
            _Pragma("unroll") for (int m = 0; m < 4; ++m)                          \
                _Pragma("unroll") for (int i = 0; i < 2; ++i)                      \
                    acc[m][(NP) + i] = __builtin_amdgcn_mfma_f32_16x16x32_bf16(    \
                        af[m][ks], BP[i][ks], acc[m][(NP) + i], 0, 0, 0);          \
        __builtin_amdgcn_s_setprio(0);                                             \
    } while (0)

    bf16x8 af[4][2];          // A frags for current tile (all 4 phases)
    bf16x8 bpA[2][2];         // n{0,1}
    bf16x8 bpB[2][2];         // n{2,3}
    bf16x8 bpC[2][2];         // n{4,5}
    bf16x8 bpD[2][2];         // n{6,7}

    // Prologue: stage tile0 chunks A0,A1,B0a | B0b,A2,A3 (FIFO = steady state),
    // drain, barrier, then issue tile0's B1 pair (stays in flight until ph1-top)
    // and read tile0's af + bpA.
    {
        unsigned short* A0b = (unsigned short*)sh;
        unsigned short* B0b = A0b + TILE_E;
        stageA(A0b, 0, 0); stageA(A0b, 1, 0); stageB(B0b, 0, 0, 0);
        stageB(B0b, 0, 1, 0); stageA(A0b, 2, 0); stageA(A0b, 3, 0);
        WAITVM(0);
        BARRIER();
        stageB(B0b, 1, 0, 0); stageB(B0b, 1, 1, 0);
#pragma unroll
        for (int m = 0; m < 4; ++m) { af[m][0] = LDA(A0b, m, sl0); af[m][1] = LDA(A0b, m, sl1); }
#pragma unroll
        for (int i = 0; i < 2; ++i) { bpA[i][0] = LDB(B0b, i, sl0); bpA[i][1] = LDB(B0b, i, sl1); }
    }

#pragma unroll 2
    for (int T = 0; T < NKT; ++T) {
        const unsigned short* Ab = sh + (T & 1) * (2 * TILE_E);
        const unsigned short* Bb = Ab + TILE_E;
        unsigned short* An = (unsigned short*)sh + ((T & 1) ^ 1) * (2 * TILE_E);
        unsigned short* Bn = An + TILE_E;
        bool pf = (T < NKT - 1);
        int kn = T + 1;

        // ---- ph0: MFMA n{0,1}; prefetch bpB; stage A0,A1,B0a -> nxt ----
        if (pf) { stageA(An, 0, kn); stageA(An, 1, kn); stageB(Bn, 0, 0, kn); }
#pragma unroll
        for (int i = 0; i < 2; ++i) { bpB[i][0] = LDB(Bb, 2 + i, sl0); bpB[i][1] = LDB(Bb, 2 + i, sl1); }
        MFMA_PAIR(0, bpA);

        // ---- ph1: drain this tile's B1, barrier (cross-wave), MFMA n{2,3} ----
        if (pf) { WAITVM(3); } else { WAITVM(0); }
        WAITLGKM0();
        BARRIER();
        if (pf) { stageB(Bn, 0, 1, kn); stageA(An, 2, kn); stageA(An, 3, kn); }
#pragma unroll
        for (int i = 0; i < 2; ++i) { bpC[i][0] = LDB(Bb, 4 + i, sl0); bpC[i][1] = LDB(Bb, 4 + i, sl1); }
        MFMA_PAIR(2, bpB);

        // ---- ph2: prefetch bpD; MFMA n{4,5} (no barrier) ----
#pragma unroll
        for (int i = 0; i < 2; ++i) { bpD[i][0] = LDB(Bb, 6 + i, sl0); bpD[i][1] = LDB(Bb, 6 + i, sl1); }
        MFMA_PAIR(4, bpC);

        // ---- ph3: drain next tile's A+B0, barrier; MFMA n{6,7}; then read
        //      next tile's af + bpA from nxt; issue next tile's B1 pair ----
        WAITVM(0);
        WAITLGKM0();
        BARRIER();
        if (pf) { stageB(Bn, 1, 0, kn); stageB(Bn, 1, 1, kn); }
        MFMA_PAIR(6, bpD);
        if (pf) {
#pragma unroll
            for (int m = 0; m < 4; ++m) { af[m][0] = LDA(An, m, sl0); af[m][1] = LDA(An, m, sl1); }
#pragma unroll
            for (int i = 0; i < 2; ++i) { bpA[i][0] = LDB(Bn, i, sl0); bpA[i][1] = LDB(Bn, i, sl1); }
        }
    }

    // Epilogue: C/D map col=lane&15, row=(lane>>4)*4+reg; fused hardtanh
#pragma unroll
    for (int m = 0; m < 4; ++m) {
#pragma unroll
        for (int n = 0; n < 8; ++n) {
#pragma unroll
            for (int r = 0; r < 4; ++r) {
                int row = m0 + wm * 64 + m * 16 + lg * 4 + r;
                int col = n0 + wn * 128 + n * 16 + lrow;
                float v = acc[m][n][r];
                v = fminf(fmaxf(v, -1.0f), 1.0f);
                out[(size_t)row * OUT_DIM + col] = v;
            }
        }
    }
}

extern "C" void kernel_launch(void* const* d_in, const int* in_sizes, int n_in,
                              void* d_out, int out_size, void* d_ws, size_t ws_size,
                              hipStream_t stream) {
    const float* x = (const float*)d_in[0];
    const float* w = (const float*)d_in[1];
    const float* gamma = (const float*)d_in[2];
    const float* beta = (const float*)d_in[3];
    float* out = (float*)d_out;

    float* wsf = (float*)d_ws;
    float* psum = wsf;                                   // 32*2048 f32
    float* psq = wsf + 32 * IN_DIM;                      // 32*2048 f32
    float* scale = wsf + 64 * IN_DIM;                    // 2048 f32
    float* shift = wsf + 65 * IN_DIM;                    // 2048 f32
    unsigned short* Bsgn = (unsigned short*)(wsf + 66 * IN_DIM);  // 8 MB
    unsigned short* Acat = Bsgn + (size_t)OUT_DIM * IN_DIM;       // 64 MB

    k_stats<<<dim3(8, 32), 256, 0, stream>>>(x, psum, psq);
    k_finalize<<<8, 256, 0, stream>>>(psum, psq, gamma, beta, scale, shift);
    k_prep_a<<<B_DIM, 256, 0, stream>>>(x, scale, shift, Acat);
    k_prep_b<<<OUT_DIM, 256, 0, stream>>>(w, Bsgn);
    k_gemm<<<NWG, 512, 0, stream>>>(Acat, Bsgn, out);
}